// Round 9
// baseline (566.469 us; speedup 1.0000x reference)
//
#include <hip/hip_runtime.h>
#include <stdint.h>

#define F 64
#define RDIM 8
#define HDIM 64
#define NPATH 5
#define EB 64            // edges per block-iteration (16 per wave)
#define PADH 72          // h_lds row stride (f16 elems), 144B: 16B-aligned rows
#define PADN 324         // w_lds row stride (f16 elems)
#define NSP 16           // species bins (S=10, padded)
#define PB 72            // BT/P row stride (f16 elems), 144B: 16B-aligned rows
#define NT 4             // N-tiles (64 out-feats / 16)

typedef _Float16 half8 __attribute__((ext_vector_type(8)));
typedef _Float16 half4 __attribute__((ext_vector_type(4)));
typedef float floatx4 __attribute__((ext_vector_type(4)));

__device__ inline half8 h8_from_f32(const float* p) {
    float4 a = ((const float4*)p)[0];
    float4 b = ((const float4*)p)[1];
    half8 h;
    h[0] = (_Float16)a.x; h[1] = (_Float16)a.y; h[2] = (_Float16)a.z; h[3] = (_Float16)a.w;
    h[4] = (_Float16)b.x; h[5] = (_Float16)b.y; h[6] = (_Float16)b.z; h[7] = (_Float16)b.w;
    return h;
}

__device__ inline half8 h8_from_f32_stride3(const float* p) {
    half8 h;
#pragma unroll
    for (int j = 0; j < 8; ++j) h[j] = (_Float16)p[j * 3];
    return h;
}

__device__ inline half8 h8_zero() {
    half8 h;
#pragma unroll
    for (int j = 0; j < 8; ++j) h[j] = (_Float16)0.f;
    return h;
}

// ---- Kernel A (MFMA): comb = linear-up, packed f16x4; + merged histograms ------
// The edge-receiver histogram (800K random atomics) and node-species histogram
// issue before the GEMM so their latency hides under MFMA work; deletes the
// separate k_hist dispatch.
__global__ __launch_bounds__(256) void k_pre_mfma(
    const float* __restrict__ nfs, const float* __restrict__ nfv,
    const float* __restrict__ Wus, const float* __restrict__ Wuv,
    half4* __restrict__ comb, int N,
    const int* __restrict__ recv, int* __restrict__ cnt, int E,
    const int* __restrict__ specie, int* __restrict__ nbin)
{
    __shared__ _Float16 BT[2][64 * PB];     // Wus^T, Wuv^T in f16, 18.4 KB
    __shared__ int lbin[NSP];
    const int tid = threadIdx.x;
    const int wave = tid >> 6, lane = tid & 63;
    const int l15 = lane & 15, lq = lane >> 4;
    const int tb0 = blockIdx.x * 64;

    if (tid < NSP) lbin[tid] = 0;
    {
        const float* srcs[2] = { Wus, Wuv };
#pragma unroll
        for (int m = 0; m < 2; ++m) {
            const float* W = srcs[m];
#pragma unroll
            for (int rep = 0; rep < 16; ++rep) {
                int id = rep * 256 + tid;           // 0..4095
                int k = id >> 6, n = id & 63;
                BT[m][n * PB + k] = (_Float16)W[k * F + n];
            }
        }
    }
    __syncthreads();

    // --- merged histograms (issue early; complete under the GEMM) ---
    {
        const int i0 = blockIdx.x * 256 + tid;
        const int stride = gridDim.x * 256;
        for (int e = i0; e < E; e += stride) atomicAdd(&cnt[recv[e]], 1);
        for (int n = i0; n < N; n += stride) atomicAdd(&lbin[specie[n]], 1);
    }

    const int tb = tb0 + wave * 16;
    const int ndA = tb + l15;

#define BFRAG(m, nt, ks) (*(const half8*)&BT[m][((nt) * 16 + l15) * PB + (ks) * 32 + lq * 8])

    floatx4 c[4][NT];
#pragma unroll
    for (int q = 0; q < 4; ++q)
#pragma unroll
        for (int nt = 0; nt < NT; ++nt) c[q][nt] = (floatx4){0.f, 0.f, 0.f, 0.f};

#pragma unroll
    for (int ks = 0; ks < 2; ++ks) {
        half8 a_s, a_v0, a_v1, a_v2;
        if (ndA < N) {
            a_s  = h8_from_f32(nfs + (size_t)ndA * F + ks * 32 + lq * 8);
            const float* vb = nfv + ((size_t)ndA * F + ks * 32 + lq * 8) * 3;
            a_v0 = h8_from_f32_stride3(vb + 0);
            a_v1 = h8_from_f32_stride3(vb + 1);
            a_v2 = h8_from_f32_stride3(vb + 2);
        } else {
            a_s = a_v0 = a_v1 = a_v2 = h8_zero();
        }
#pragma unroll
        for (int nt = 0; nt < NT; ++nt) {
            half8 bs = BFRAG(0, nt, ks);
            half8 bv = BFRAG(1, nt, ks);
            c[0][nt] = __builtin_amdgcn_mfma_f32_16x16x32_f16(a_s,  bs, c[0][nt], 0, 0, 0);
            c[1][nt] = __builtin_amdgcn_mfma_f32_16x16x32_f16(a_v0, bv, c[1][nt], 0, 0, 0);
            c[2][nt] = __builtin_amdgcn_mfma_f32_16x16x32_f16(a_v1, bv, c[2][nt], 0, 0, 0);
            c[3][nt] = __builtin_amdgcn_mfma_f32_16x16x32_f16(a_v2, bv, c[3][nt], 0, 0, 0);
        }
    }
#undef BFRAG

#pragma unroll
    for (int r = 0; r < 4; ++r) {
        const int nd = tb + lq * 4 + r;
        if (nd < N) {
#pragma unroll
            for (int nt = 0; nt < NT; ++nt) {
                half4 o;
                o[0] = (_Float16)c[0][nt][r];
                o[1] = (_Float16)c[1][nt][r];
                o[2] = (_Float16)c[2][nt][r];
                o[3] = (_Float16)c[3][nt][r];
                comb[(size_t)nd * F + nt * 16 + l15] = o;
            }
        }
    }

    __syncthreads();
    if (tid < NSP && lbin[tid] > 0) atomicAdd(&nbin[tid], lbin[tid]);
}

// scanA: per-block (1024 elems) sums, coalesced
__global__ __launch_bounds__(1024) void k_scanA(
    const int* __restrict__ cnt, int* __restrict__ bsum, int N)
{
    __shared__ int lsum[1024];
    const int tid = threadIdx.x;
    const int i = blockIdx.x * 1024 + tid;
    int x = (i < N) ? cnt[i] : 0;
    lsum[tid] = x;
    __syncthreads();
    for (int off = 512; off > 0; off >>= 1) {
        if (tid < off) lsum[tid] += lsum[tid + off];
        __syncthreads();
    }
    if (tid == 0) bsum[blockIdx.x] = lsum[0];
}

// scanB: exclusive scan of block sums + 64-aligned species-run starts
__global__ __launch_bounds__(64) void k_scanB(
    int* __restrict__ bsum, int nb,
    const int* __restrict__ nbin, int* __restrict__ ncur)
{
    const int lane = threadIdx.x;
    int carry = 0;
    for (int base = 0; base < nb; base += 64) {
        const int idx = base + lane;
        int v = (idx < nb) ? bsum[idx] : 0;
        int incl = v;
#pragma unroll
        for (int off = 1; off < 64; off <<= 1) {
            int u = __shfl_up(incl, off, 64);
            if (lane >= off) incl += u;
        }
        int tot = __shfl(incl, 63, 64);
        if (idx < nb) bsum[idx] = incl - v + carry;
        carry += tot;
    }
    if (lane == 0) {
        int run = 0;
        for (int s = 0; s < NSP; ++s) {
            ncur[s] = run;
            run += ((nbin[s] + 63) >> 6) << 6;
        }
    }
}

// scanC: per-block LDS scan + block offset -> global exclusive prefix (cursor)
__global__ __launch_bounds__(1024) void k_scanC(
    const int* __restrict__ cnt, const int* __restrict__ bsum,
    int* __restrict__ cursor, int N)
{
    __shared__ int lsum[1024];
    const int tid = threadIdx.x;
    const int i = blockIdx.x * 1024 + tid;
    int x = (i < N) ? cnt[i] : 0;
    lsum[tid] = x;
    __syncthreads();
    int acc = x;
    for (int off = 1; off < 1024; off <<= 1) {
        int add = (tid >= off) ? lsum[tid - off] : 0;
        __syncthreads();
        acc += add;
        lsum[tid] = acc;
        __syncthreads();
    }
    if (i < N) cursor[i] = acc - x + bsum[blockIdx.x];
}

// edge scatter + node species scatter (merged; grid must cover N in one pass)
// Plain stores: NT-store variant regressed ~10 us (round 8).
__global__ __launch_bounds__(256) void k_scatter(
    const int* __restrict__ recv, const int* __restrict__ send,
    int* __restrict__ cursor, int* __restrict__ perm,
    int2* __restrict__ srsort, int E,
    const int* __restrict__ specie, int* __restrict__ ncur,
    int* __restrict__ nperm, int N)
{
    __shared__ int lbin[NSP], lbase[NSP], lcur[NSP];
    const int tid = threadIdx.x;
    const int i0 = blockIdx.x * 256 + tid;
    const int stride = gridDim.x * 256;
    for (int e = i0; e < E; e += stride) {
        int r = recv[e];
        int p = atomicAdd(&cursor[r], 1);
        perm[p] = e;
        srsort[p] = make_int2(send[e], r);
    }
    if (tid < NSP) { lbin[tid] = 0; lcur[tid] = 0; }
    __syncthreads();
    int sp = -1;
    if (i0 < N) { sp = specie[i0]; atomicAdd(&lbin[sp], 1); }
    __syncthreads();
    if (tid < NSP && lbin[tid] > 0) lbase[tid] = atomicAdd(&ncur[tid], lbin[tid]);
    __syncthreads();
    if (i0 < N) {
        int off = atomicAdd(&lcur[sp], 1);
        nperm[lbase[sp] + off] = i0;
    }
}

// ---- Kernel B: radial MLP (MFMA) + tensor product + sorted run-accumulation ----
// EB=64 / 3 blocks/CU: proven local optimum (EB=32 + 6/CU regressed 3x via
// cross-XCD agg-line thrash — round 7). XCD-chunked block swizzle: each XCD
// gets a contiguous span of edge windows so receiver-run boundary lines stay
// in one L2.
__global__ __launch_bounds__(256, 3) void k_edge(
    const float* __restrict__ vecs, const float* __restrict__ re,
    const float* __restrict__ Wr1, const float* __restrict__ Wr2,
    const int* __restrict__ perm, const int2* __restrict__ srsort,
    const half4* __restrict__ comb,
    float* __restrict__ agg_s, float* __restrict__ agg_v, int E)
{
    __shared__ _Float16 h_lds[EB * PADH];   // ~9 KB
    __shared__ _Float16 w_lds[EB * PADN];   // ~40.5 KB
    const int tid = threadIdx.x;
    const int wave = tid >> 6, lane = tid & 63;
    const int l15 = lane & 15, lq = lane >> 4;

    // XCD-aware swizzle (gridDim.x must be a multiple of 8 -> bijective)
    const int nwg = gridDim.x;
    const int wid = (blockIdx.x & 7) * (nwg >> 3) + (blockIdx.x >> 3);

    // Persistent B-fragments: this wave's 80-col slice of W_r2 (f16).
    half8 bfrag[5][2];
#pragma unroll
    for (int nt = 0; nt < 5; ++nt)
#pragma unroll
        for (int ks = 0; ks < 2; ++ks)
#pragma unroll
            for (int j = 0; j < 8; ++j) {
                int k = ks * 32 + lq * 8 + j;
                int n = wave * 80 + nt * 16 + l15;
                bfrag[nt][ks][j] = (_Float16)Wr2[k * (NPATH * F) + n];
            }

    float w1r[RDIM];
#pragma unroll
    for (int r = 0; r < RDIM; ++r) w1r[r] = Wr1[r * HDIM + lane];

    const int niter = (E + EB - 1) / EB;
    for (int it = wid; it < niter; it += nwg) {
        const int base = it * EB;
        const bool full = (base + EB <= E);

        // --- phase 1: h for this wave's 16 (sorted) edges; lane = hidden unit ---
        if (full) {
            const int ew = base + wave * 16;
            int pm[16];
#pragma unroll
            for (int j = 0; j < 4; ++j)
                ((int4*)pm)[j] = ((const int4*)(perm + ew))[j];
            float4 ra[4], rb[4];
#pragma unroll
            for (int j = 0; j < 4; ++j) {
                const float4* rp = (const float4*)(re + (size_t)pm[j] * RDIM);
                ra[j] = rp[0]; rb[j] = rp[1];
            }
#pragma unroll
            for (int t = 0; t < 16; ++t) {
                float4 A = ra[t & 3], B = rb[t & 3];
                if (t < 12) {
                    const float4* rp = (const float4*)(re + (size_t)pm[t + 4] * RDIM);
                    ra[t & 3] = rp[0]; rb[t & 3] = rp[1];
                }
                float h = A.x * w1r[0] + A.y * w1r[1] + A.z * w1r[2] + A.w * w1r[3]
                        + B.x * w1r[4] + B.y * w1r[5] + B.z * w1r[6] + B.w * w1r[7];
                h = h / (1.f + __expf(-h));   // silu
                h_lds[(wave * 16 + t) * PADH + lane] = (_Float16)h;
            }
        } else {
            for (int t = 0; t < 16; ++t) {
                const int eloc = wave * 16 + t;
                const int e = base + eloc;
                float h = 0.f;
                if (e < E) {
                    const int pe = perm[e];
                    const float4* rp = (const float4*)(re + (size_t)pe * RDIM);
                    float4 A = rp[0], B = rp[1];
                    h = A.x * w1r[0] + A.y * w1r[1] + A.z * w1r[2] + A.w * w1r[3]
                      + B.x * w1r[4] + B.y * w1r[5] + B.z * w1r[6] + B.w * w1r[7];
                    h = h / (1.f + __expf(-h));
                }
                h_lds[eloc * PADH + lane] = (_Float16)h;
            }
        }
        __syncthreads();

        // --- phase 2: W(64 x 320) = H(64 x 64) @ Wr2(64 x 320) via MFMA ---
        floatx4 c[4][5];
#pragma unroll
        for (int mt = 0; mt < 4; ++mt)
#pragma unroll
            for (int nt = 0; nt < 5; ++nt)
                c[mt][nt] = (floatx4){0.f, 0.f, 0.f, 0.f};
#pragma unroll
        for (int ks = 0; ks < 2; ++ks) {
            half8 a[4];
#pragma unroll
            for (int mt = 0; mt < 4; ++mt)
                a[mt] = *(const half8*)&h_lds[(mt * 16 + l15) * PADH + ks * 32 + lq * 8];
#pragma unroll
            for (int mt = 0; mt < 4; ++mt)
#pragma unroll
                for (int nt = 0; nt < 5; ++nt)
                    c[mt][nt] = __builtin_amdgcn_mfma_f32_16x16x32_f16(
                        a[mt], bfrag[nt][ks], c[mt][nt], 0, 0, 0);
        }
#pragma unroll
        for (int mt = 0; mt < 4; ++mt)
#pragma unroll
            for (int nt = 0; nt < 5; ++nt)
#pragma unroll
                for (int r = 0; r < 4; ++r) {
                    int row = mt * 16 + lq * 4 + r;
                    int col = wave * 80 + nt * 16 + l15;
                    w_lds[row * PADN + col] = (_Float16)c[mt][nt][r];
                }
        __syncthreads();

        // --- phase 3: tensor product + run-accumulate over sorted receivers ---
        if (full) {
            const int ew = base + wave * 16;
            int pm[16];
            int2 sr[16];
#pragma unroll
            for (int j = 0; j < 4; ++j)
                ((int4*)pm)[j] = ((const int4*)(perm + ew))[j];
#pragma unroll
            for (int j = 0; j < 8; ++j)
                ((int4*)sr)[j] = ((const int4*)(srsort + ew))[j];
            half4 gb[4];
            float vxr[4], vyr[4], vzr[4];
#pragma unroll
            for (int j = 0; j < 4; ++j) {
                gb[j] = comb[(size_t)sr[j].x * F + lane];
                const float* vp = vecs + (size_t)pm[j] * 3;
                vxr[j] = vp[0]; vyr[j] = vp[1]; vzr[j] = vp[2];
            }
            float accs = 0.f, acc0 = 0.f, acc1 = 0.f, acc2 = 0.f;
            int cur = sr[0].y;
#pragma unroll
            for (int t = 0; t < 16; ++t) {
                half4 g = gb[t & 3];
                float vx = vxr[t & 3], vy = vyr[t & 3], vz = vzr[t & 3];
                if (t < 12) {
                    gb[t & 3] = comb[(size_t)sr[t + 4].x * F + lane];
                    const float* vp = vecs + (size_t)pm[t + 4] * 3;
                    vxr[t & 3] = vp[0]; vyr[t & 3] = vp[1]; vzr[t & 3] = vp[2];
                }
                const int eloc = wave * 16 + t;
                float nrm = sqrtf(vx * vx + vy * vy + vz * vz);
                float inv = 1.f / (nrm + 1e-9f);
                float Yx = vx * inv, Yy = vy * inv, Yz = vz * inv;
                float w0  = (float)w_lds[eloc * PADN + 0 * F + lane];
                float w1p = (float)w_lds[eloc * PADN + 1 * F + lane];
                float w2p = (float)w_lds[eloc * PADN + 2 * F + lane];
                float w3p = (float)w_lds[eloc * PADN + 3 * F + lane];
                float w4p = (float)w_lds[eloc * PADN + 4 * F + lane];
                float xs = (float)g[0], x0 = (float)g[1], x1 = (float)g[2], x2 = (float)g[3];
                float dvY = x0 * Yx + x1 * Yy + x2 * Yz;
                float ms = w0 * xs + w3p * dvY;
                float m0 = w1p * xs * Yx + w2p * x0 + w4p * (x1 * Yz - x2 * Yy);
                float m1 = w1p * xs * Yy + w2p * x1 + w4p * (x2 * Yx - x0 * Yz);
                float m2 = w1p * xs * Yz + w2p * x2 + w4p * (x0 * Yy - x1 * Yx);
                if (sr[t].y != cur) {
                    float* asb = agg_s + (size_t)cur * F;
                    float* avb = agg_v + (size_t)cur * 3 * F;
                    unsafeAtomicAdd(&asb[lane], accs);
                    unsafeAtomicAdd(&avb[lane], acc0);
                    unsafeAtomicAdd(&avb[F + lane], acc1);
                    unsafeAtomicAdd(&avb[2 * F + lane], acc2);
                    accs = acc0 = acc1 = acc2 = 0.f;
                    cur = sr[t].y;
                }
                accs += ms; acc0 += m0; acc1 += m1; acc2 += m2;
            }
            {
                float* asb = agg_s + (size_t)cur * F;
                float* avb = agg_v + (size_t)cur * 3 * F;
                unsafeAtomicAdd(&asb[lane], accs);
                unsafeAtomicAdd(&avb[lane], acc0);
                unsafeAtomicAdd(&avb[F + lane], acc1);
                unsafeAtomicAdd(&avb[2 * F + lane], acc2);
            }
        } else {
            for (int t = 0; t < 16; ++t) {
                const int eloc = wave * 16 + t;
                const int e = base + eloc;
                if (e >= E) break;
                const int pe = perm[e];
                const int2 sr = srsort[e];
                const int snd = sr.x, rcv = sr.y;
                const float* vp = vecs + (size_t)pe * 3;
                float vx = vp[0], vy = vp[1], vz = vp[2];
                float nrm = sqrtf(vx * vx + vy * vy + vz * vz);
                float inv = 1.f / (nrm + 1e-9f);
                float Yx = vx * inv, Yy = vy * inv, Yz = vz * inv;
                half4 g = comb[(size_t)snd * F + lane];
                float w0  = (float)w_lds[eloc * PADN + 0 * F + lane];
                float w1p = (float)w_lds[eloc * PADN + 1 * F + lane];
                float w2p = (float)w_lds[eloc * PADN + 2 * F + lane];
                float w3p = (float)w_lds[eloc * PADN + 3 * F + lane];
                float w4p = (float)w_lds[eloc * PADN + 4 * F + lane];
                float xs = (float)g[0], x0 = (float)g[1], x1 = (float)g[2], x2 = (float)g[3];
                float dvY = x0 * Yx + x1 * Yy + x2 * Yz;
                float ms = w0 * xs + w3p * dvY;
                float m0 = w1p * xs * Yx + w2p * x0 + w4p * (x1 * Yz - x2 * Yy);
                float m1 = w1p * xs * Yy + w2p * x1 + w4p * (x2 * Yx - x0 * Yz);
                float m2 = w1p * xs * Yz + w2p * x2 + w4p * (x0 * Yy - x1 * Yx);
                float* asb = agg_s + (size_t)rcv * F;
                float* avb = agg_v + (size_t)rcv * 3 * F;
                unsafeAtomicAdd(&asb[lane], ms);
                unsafeAtomicAdd(&avb[lane], m0);
                unsafeAtomicAdd(&avb[F + lane], m1);
                unsafeAtomicAdd(&avb[2 * F + lane], m2);
            }
        }
    }
}

// ---- Kernel C (MFMA): linear-down, sym contraction, skip, readout --------------
__global__ __launch_bounds__(256) void k_post_mfma(
    const float* __restrict__ agg_s, const float* __restrict__ agg_v,
    const float* __restrict__ nfs, const float* __restrict__ nfv,
    const float* __restrict__ Wds, const float* __restrict__ Wdv,
    const float* __restrict__ wss, const float* __restrict__ wsv,
    const float* __restrict__ WLs, const float* __restrict__ WLv,
    const float* __restrict__ Wsks, const float* __restrict__ Wskv,
    const float* __restrict__ Wout, const int* __restrict__ specie,
    const int* __restrict__ nperm,
    float* __restrict__ out0, float* __restrict__ out_fs,
    float* __restrict__ out_fv, int N)
{
    __shared__ _Float16 BT[6][64 * PB];     // transposed f16 weights [n][k], 55.3 KB
    __shared__ _Float16 P_lds[4][16 * PB];  // per-wave P transpose tile, 9.2 KB
    const int tid = threadIdx.x;
    const int wave = tid >> 6, lane = tid & 63;
    const int l15 = lane & 15, lq = lane >> 4;
    const int tb0 = blockIdx.x * 64;

    const int nfirst = nperm[tb0];
    const int sp = (nfirst < 0) ? 0 : specie[nfirst];

    // --- stage 6 weight matrices transposed into LDS (once per block) ---
    {
        const float* srcs[6] = { Wds, Wdv,
                                 Wsks + (size_t)sp * F * F, Wskv + (size_t)sp * F * F,
                                 WLs, WLv };
#pragma unroll
        for (int m = 0; m < 6; ++m) {
            const float* W = srcs[m];
#pragma unroll
            for (int rep = 0; rep < 16; ++rep) {
                int id = rep * 256 + tid;           // 0..4095
                int k = id >> 6, n = id & 63;
                BT[m][n * PB + k] = (_Float16)W[k * F + n];
            }
        }
    }
    __syncthreads();

    const int tb = tb0 + wave * 16;
    const int ndA = nperm[tb + l15];        // A-row node for this lane's m=l15
    int ndr[4];
#pragma unroll
    for (int r = 0; r < 4; ++r) ndr[r] = nperm[tb + lq * 4 + r];

#define BFRAG(m, nt, ks) (*(const half8*)&BT[m][((nt) * 16 + l15) * PB + (ks) * 32 + lq * 8])

    // --- skip GEMM: csk[q][nt] = nf @ Wsk  (q: 0=s, 1..3=v components) ---
    floatx4 csk[4][NT];
#pragma unroll
    for (int q = 0; q < 4; ++q)
#pragma unroll
        for (int nt = 0; nt < NT; ++nt) csk[q][nt] = (floatx4){0.f, 0.f, 0.f, 0.f};
#pragma unroll
    for (int ks = 0; ks < 2; ++ks) {
        half8 a_s, a_v0, a_v1, a_v2;
        if (ndA >= 0) {
            a_s  = h8_from_f32(nfs + (size_t)ndA * F + ks * 32 + lq * 8);
            const float* vb = nfv + ((size_t)ndA * F + ks * 32 + lq * 8) * 3;
            a_v0 = h8_from_f32_stride3(vb + 0);
            a_v1 = h8_from_f32_stride3(vb + 1);
            a_v2 = h8_from_f32_stride3(vb + 2);
        } else {
            a_s = a_v0 = a_v1 = a_v2 = h8_zero();
        }
#pragma unroll
        for (int nt = 0; nt < NT; ++nt) {
            half8 bs = BFRAG(2, nt, ks);
            half8 bv = BFRAG(3, nt, ks);
            csk[0][nt] = __builtin_amdgcn_mfma_f32_16x16x32_f16(a_s,  bs, csk[0][nt], 0, 0, 0);
            csk[1][nt] = __builtin_amdgcn_mfma_f32_16x16x32_f16(a_v0, bv, csk[1][nt], 0, 0, 0);
            csk[2][nt] = __builtin_amdgcn_mfma_f32_16x16x32_f16(a_v1, bv, csk[2][nt], 0, 0, 0);
            csk[3][nt] = __builtin_amdgcn_mfma_f32_16x16x32_f16(a_v2, bv, csk[3][nt], 0, 0, 0);
        }
    }

    // --- down GEMM: cdn[q][nt] = agg @ Wd ---
    floatx4 cdn[4][NT];
#pragma unroll
    for (int q = 0; q < 4; ++q)
#pragma unroll
        for (int nt = 0; nt < NT; ++nt) cdn[q][nt] = (floatx4){0.f, 0.f, 0.f, 0.f};
#pragma unroll
    for (int ks = 0; ks < 2; ++ks) {
        half8 a_s, a_v0, a_v1, a_v2;
        if (ndA >= 0) {
            a_s  = h8_from_f32(agg_s + (size_t)ndA * F + ks * 32 + lq * 8);
            const float* vb = agg_v + (size_t)ndA * 3 * F + ks * 32 + lq * 8;
            a_v0 = h8_from_f32(vb);
            a_v1 = h8_from_f32(vb + F);
            a_v2 = h8_from_f32(vb + 2 * F);
        } else {
            a_s = a_v0 = a_v1 = a_v2 = h8_zero();
        }
#pragma unroll
        for (int nt = 0; nt < NT; ++nt) {
            half8 bs = BFRAG(0, nt, ks);
            half8 bv = BFRAG(1, nt, ks);
            cdn[0][nt] = __builtin_amdgcn_mfma_f32_16x16x32_f16(a_s,  bs, cdn[0][nt], 0, 0, 0);
            cdn[1][nt] = __builtin_amdgcn_mfma_f32_16x16x32_f16(a_v0, bv, cdn[1][nt], 0, 0, 0);
            cdn[2][nt] = __builtin_amdgcn_mfma_f32_16x16x32_f16(a_v1, bv, cdn[2][nt], 0, 0, 0);
            cdn[3][nt] = __builtin_amdgcn_mfma_f32_16x16x32_f16(a_v2, bv, cdn[3][nt], 0, 0, 0);
        }
    }

    // --- sym contraction, elementwise in C layout; result overwrites cdn ---
#pragma unroll
    for (int nt = 0; nt < NT; ++nt) {
        const int g = nt * 16 + l15;
        float a0 = wss[(sp * 3 + 0) * F + g];
        float a1 = wss[(sp * 3 + 1) * F + g];
        float a2 = wss[(sp * 3 + 2) * F + g];
        float b0 = wsv[(sp * 2 + 0) * F + g];
        float b1 = wsv[(sp * 2 + 1) * F + g];
#pragma unroll
        for (int r = 0; r < 4; ++r) {
            const float inv = 0.25f;   // 1/sqrt(16)
            float s2  = cdn[0][nt][r] * inv;
            float v20 = cdn[1][nt][r] * inv;
            float v21 = cdn[2][nt][r] * inv;
            float v22 = cdn[3][nt][r] * inv;
            cdn[0][nt][r] = a0 * s2 + a1 * s2 * s2
                          + a2 * (v20 * v20 + v21 * v21 + v22 * v22);
            cdn[1][nt][r] = b0 * v20 + b1 * s2 * v20;
            cdn[2][nt][r] = b0 * v21 + b1 * s2 * v21;
            cdn[3][nt][r] = b0 * v22 + b1 * s2 * v22;
        }
    }

    // --- final GEMM per quantity: csk[q] += P_q @ WL  (via per-wave LDS transpose)
#pragma unroll
    for (int q = 0; q < 4; ++q) {
#pragma unroll
        for (int nt = 0; nt < NT; ++nt)
#pragma unroll
            for (int r = 0; r < 4; ++r)
                P_lds[wave][(lq * 4 + r) * PB + nt * 16 + l15] = (_Float16)cdn[q][nt][r];
        __syncthreads();
        half8 ap0 = *(const half8*)&P_lds[wave][l15 * PB + 0 * 32 + lq * 8];
        half8 ap1 = *(const half8*)&P_lds[wave][l15 * PB + 1 * 32 + lq * 8];
        const int bm = (q == 0) ? 4 : 5;
#pragma unroll
        for (int nt = 0; nt < NT; ++nt) {
            csk[q][nt] = __builtin_amdgcn_mfma_f32_16x16x32_f16(ap0, BFRAG(bm, nt, 0), csk[q][nt], 0, 0, 0);
            csk[q][nt] = __builtin_amdgcn_mfma_f32_16x16x32_f16(ap1, BFRAG(bm, nt, 1), csk[q][nt], 0, 0, 0);
        }
        __syncthreads();
    }
#undef BFRAG

    // --- stores + readout ---
    float wo[NT];
#pragma unroll
    for (int nt = 0; nt < NT; ++nt) wo[nt] = Wout[nt * 16 + l15];
#pragma unroll
    for (int r = 0; r < 4; ++r) {
        const int nd = ndr[r];
        float po = 0.f;
        if (nd >= 0) {
#pragma unroll
            for (int nt = 0; nt < NT; ++nt) {
                const int g = nt * 16 + l15;
                float fs = csk[0][nt][r];
                out_fs[(size_t)nd * F + g] = fs;
                po += fs * wo[nt];
                float* fvp = out_fv + ((size_t)nd * F + g) * 3;
                fvp[0] = csk[1][nt][r];
                fvp[1] = csk[2][nt][r];
                fvp[2] = csk[3][nt][r];
            }
            po += __shfl_xor(po, 1, 64);
            po += __shfl_xor(po, 2, 64);
            po += __shfl_xor(po, 4, 64);
            po += __shfl_xor(po, 8, 64);
            if (l15 == 0) out0[nd] = po;
        }
    }
}

extern "C" void kernel_launch(void* const* d_in, const int* in_sizes, int n_in,
                              void* d_out, int out_size, void* d_ws, size_t ws_size,
                              hipStream_t stream)
{
    const float* vectors = (const float*)d_in[0];
    const float* nfs  = (const float*)d_in[1];
    const float* nfv  = (const float*)d_in[2];
    const float* re   = (const float*)d_in[3];
    const float* Wus  = (const float*)d_in[4];
    const float* Wuv  = (const float*)d_in[5];
    const float* Wr1  = (const float*)d_in[6];
    const float* Wr2  = (const float*)d_in[7];
    const float* Wds  = (const float*)d_in[8];
    const float* Wdv  = (const float*)d_in[9];
    const float* wss  = (const float*)d_in[10];
    const float* wsv  = (const float*)d_in[11];
    const float* WLs  = (const float*)d_in[12];
    const float* WLv  = (const float*)d_in[13];
    const float* Wsks = (const float*)d_in[14];
    const float* Wskv = (const float*)d_in[15];
    const float* Wout = (const float*)d_in[16];
    const int* specie    = (const int*)d_in[17];
    const int* senders   = (const int*)d_in[18];
    const int* receivers = (const int*)d_in[19];

    const int N = in_sizes[1] / F;   // 50000
    const int E = in_sizes[18];      // 800000

    const size_t NF = (size_t)N * F;
    const int NPAD_MAX = N + NSP * 64 + 64;   // species runs padded to 64
    // Workspace layout (~87.4 MB, under the 102.4 MB proven-safe footprint):
    //   comb   : NF half4 (8 B)        = 25.6 MB
    //   agg_s  : NF f32                = 12.8 MB
    //   agg_v  : 3NF f32               = 38.4 MB
    //   perm   : E ints                =  3.2 MB
    //   srsort : E int2                =  6.4 MB
    //   cnt,nbin,ncur,cursor,bsum,nperm: ~0.6 MB
    half4* comb  = (half4*)d_ws;
    float* agg_s = (float*)((char*)d_ws + NF * sizeof(half4));
    float* agg_v = agg_s + NF;
    int*   perm  = (int*)(agg_v + 3 * NF);
    int2*  srsort = (int2*)(perm + E);
    int*   cnt    = (int*)(srsort + E);     // [N]
    int*   nbin   = cnt + N;                // [NSP] (zeroed with cnt)
    int*   ncur   = nbin + NSP;             // [NSP]
    int*   cursor = ncur + NSP;             // [N]
    int*   bsum   = cursor + N;             // [<=64]
    int*   nperm  = bsum + 64;              // [NPAD_MAX]

    hipMemsetAsync(agg_s, 0, (size_t)4 * NF * sizeof(float), stream);
    hipMemsetAsync(cnt, 0, (size_t)(N + NSP) * sizeof(int), stream);
    hipMemsetAsync(nperm, 0xFF, (size_t)NPAD_MAX * sizeof(int), stream);

    const int nb64 = (N + 63) / 64;             // k_pre_mfma blocks (782)
    const int nbs = (N + 1023) / 1024;          // scan blocks (49)
    const int nbp = (N + NSP * 64 + 63) / 64;   // k_post_mfma blocks

    k_pre_mfma<<<nb64, 256, 0, stream>>>(nfs, nfv, Wus, Wuv, comb, N,
                                         receivers, cnt, E, specie, nbin);
    k_scanA<<<nbs, 1024, 0, stream>>>(cnt, bsum, N);
    k_scanB<<<1, 64, 0, stream>>>(bsum, nbs, nbin, ncur);
    k_scanC<<<nbs, 1024, 0, stream>>>(cnt, bsum, cursor, N);
    k_scatter<<<1024, 256, 0, stream>>>(receivers, senders, cursor, perm,
                                        srsort, E, specie, ncur, nperm, N);
    k_edge<<<2048, 256, 0, stream>>>(vectors, re, Wr1, Wr2, perm, srsort,
                                     comb, agg_s, agg_v, E);
    float* out0   = (float*)d_out;
    float* out_fs = out0 + N;
    float* out_fv = out_fs + (size_t)N * F;
    k_post_mfma<<<nbp, 256, 0, stream>>>(agg_s, agg_v, nfs, nfv, Wds, Wdv,
                                         wss, wsv, WLs, WLv, Wsks, Wskv,
                                         Wout, specie, nperm,
                                         out0, out_fs, out_fv, N);
}

// Round 10
// 537.609 us; speedup vs baseline: 1.0537x; 1.0537x over previous
//
#include <hip/hip_runtime.h>
#include <stdint.h>

#define F 64
#define RDIM 8
#define HDIM 64
#define NPATH 5
#define EB 64            // edges per block-iteration (16 per wave)
#define PADH 72          // h_lds row stride (f16 elems), 144B: 16B-aligned rows
#define PADN 324         // w_lds row stride (f16 elems)
#define NSP 16           // species bins (S=10, padded)
#define PB 72            // BT/P row stride (f16 elems), 144B: 16B-aligned rows
#define NT 4             // N-tiles (64 out-feats / 16)

typedef _Float16 half8 __attribute__((ext_vector_type(8)));
typedef _Float16 half4 __attribute__((ext_vector_type(4)));
typedef float floatx4 __attribute__((ext_vector_type(4)));

// esort packing: bits[63:32]=edge id (E<2^20), [31:16]=receiver, [15:0]=sender
// (valid because N=50000 < 2^16)
#define ES_E(v)   ((int)((v) >> 32))
#define ES_R(v)   ((int)(((v) >> 16) & 0xFFFFu))
#define ES_S(v)   ((int)((v) & 0xFFFFu))

__device__ inline half8 h8_from_f32(const float* p) {
    float4 a = ((const float4*)p)[0];
    float4 b = ((const float4*)p)[1];
    half8 h;
    h[0] = (_Float16)a.x; h[1] = (_Float16)a.y; h[2] = (_Float16)a.z; h[3] = (_Float16)a.w;
    h[4] = (_Float16)b.x; h[5] = (_Float16)b.y; h[6] = (_Float16)b.z; h[7] = (_Float16)b.w;
    return h;
}

__device__ inline half8 h8_from_f32_stride3(const float* p) {
    half8 h;
#pragma unroll
    for (int j = 0; j < 8; ++j) h[j] = (_Float16)p[j * 3];
    return h;
}

__device__ inline half8 h8_zero() {
    half8 h;
#pragma unroll
    for (int j = 0; j < 8; ++j) h[j] = (_Float16)0.f;
    return h;
}

// ---- Kernel A (MFMA): comb = linear-up, packed f16x4; + merged histograms ------
__global__ __launch_bounds__(256) void k_pre_mfma(
    const float* __restrict__ nfs, const float* __restrict__ nfv,
    const float* __restrict__ Wus, const float* __restrict__ Wuv,
    half4* __restrict__ comb, int N,
    const int* __restrict__ recv, int* __restrict__ cnt, int E,
    const int* __restrict__ specie, int* __restrict__ nbin)
{
    __shared__ _Float16 BT[2][64 * PB];     // Wus^T, Wuv^T in f16, 18.4 KB
    __shared__ int lbin[NSP];
    const int tid = threadIdx.x;
    const int wave = tid >> 6, lane = tid & 63;
    const int l15 = lane & 15, lq = lane >> 4;
    const int tb0 = blockIdx.x * 64;

    if (tid < NSP) lbin[tid] = 0;
    {
        const float* srcs[2] = { Wus, Wuv };
#pragma unroll
        for (int m = 0; m < 2; ++m) {
            const float* W = srcs[m];
#pragma unroll
            for (int rep = 0; rep < 16; ++rep) {
                int id = rep * 256 + tid;           // 0..4095
                int k = id >> 6, n = id & 63;
                BT[m][n * PB + k] = (_Float16)W[k * F + n];
            }
        }
    }
    __syncthreads();

    // --- merged histograms (issue early; complete under the GEMM) ---
    {
        const int i0 = blockIdx.x * 256 + tid;
        const int stride = gridDim.x * 256;
        for (int e = i0; e < E; e += stride) atomicAdd(&cnt[recv[e]], 1);
        for (int n = i0; n < N; n += stride) atomicAdd(&lbin[specie[n]], 1);
    }

    const int tb = tb0 + wave * 16;
    const int ndA = tb + l15;

#define BFRAG(m, nt, ks) (*(const half8*)&BT[m][((nt) * 16 + l15) * PB + (ks) * 32 + lq * 8])

    floatx4 c[4][NT];
#pragma unroll
    for (int q = 0; q < 4; ++q)
#pragma unroll
        for (int nt = 0; nt < NT; ++nt) c[q][nt] = (floatx4){0.f, 0.f, 0.f, 0.f};

#pragma unroll
    for (int ks = 0; ks < 2; ++ks) {
        half8 a_s, a_v0, a_v1, a_v2;
        if (ndA < N) {
            a_s  = h8_from_f32(nfs + (size_t)ndA * F + ks * 32 + lq * 8);
            const float* vb = nfv + ((size_t)ndA * F + ks * 32 + lq * 8) * 3;
            a_v0 = h8_from_f32_stride3(vb + 0);
            a_v1 = h8_from_f32_stride3(vb + 1);
            a_v2 = h8_from_f32_stride3(vb + 2);
        } else {
            a_s = a_v0 = a_v1 = a_v2 = h8_zero();
        }
#pragma unroll
        for (int nt = 0; nt < NT; ++nt) {
            half8 bs = BFRAG(0, nt, ks);
            half8 bv = BFRAG(1, nt, ks);
            c[0][nt] = __builtin_amdgcn_mfma_f32_16x16x32_f16(a_s,  bs, c[0][nt], 0, 0, 0);
            c[1][nt] = __builtin_amdgcn_mfma_f32_16x16x32_f16(a_v0, bv, c[1][nt], 0, 0, 0);
            c[2][nt] = __builtin_amdgcn_mfma_f32_16x16x32_f16(a_v1, bv, c[2][nt], 0, 0, 0);
            c[3][nt] = __builtin_amdgcn_mfma_f32_16x16x32_f16(a_v2, bv, c[3][nt], 0, 0, 0);
        }
    }
#undef BFRAG

#pragma unroll
    for (int r = 0; r < 4; ++r) {
        const int nd = tb + lq * 4 + r;
        if (nd < N) {
#pragma unroll
            for (int nt = 0; nt < NT; ++nt) {
                half4 o;
                o[0] = (_Float16)c[0][nt][r];
                o[1] = (_Float16)c[1][nt][r];
                o[2] = (_Float16)c[2][nt][r];
                o[3] = (_Float16)c[3][nt][r];
                comb[(size_t)nd * F + nt * 16 + l15] = o;
            }
        }
    }

    __syncthreads();
    if (tid < NSP && lbin[tid] > 0) atomicAdd(&nbin[tid], lbin[tid]);
}

// scanA: per-block (1024 elems) sums, coalesced
__global__ __launch_bounds__(1024) void k_scanA(
    const int* __restrict__ cnt, int* __restrict__ bsum, int N)
{
    __shared__ int lsum[1024];
    const int tid = threadIdx.x;
    const int i = blockIdx.x * 1024 + tid;
    int x = (i < N) ? cnt[i] : 0;
    lsum[tid] = x;
    __syncthreads();
    for (int off = 512; off > 0; off >>= 1) {
        if (tid < off) lsum[tid] += lsum[tid + off];
        __syncthreads();
    }
    if (tid == 0) bsum[blockIdx.x] = lsum[0];
}

// scanB: exclusive scan of block sums + 64-aligned species-run starts
__global__ __launch_bounds__(64) void k_scanB(
    int* __restrict__ bsum, int nb,
    const int* __restrict__ nbin, int* __restrict__ ncur)
{
    const int lane = threadIdx.x;
    int carry = 0;
    for (int base = 0; base < nb; base += 64) {
        const int idx = base + lane;
        int v = (idx < nb) ? bsum[idx] : 0;
        int incl = v;
#pragma unroll
        for (int off = 1; off < 64; off <<= 1) {
            int u = __shfl_up(incl, off, 64);
            if (lane >= off) incl += u;
        }
        int tot = __shfl(incl, 63, 64);
        if (idx < nb) bsum[idx] = incl - v + carry;
        carry += tot;
    }
    if (lane == 0) {
        int run = 0;
        for (int s = 0; s < NSP; ++s) {
            ncur[s] = run;
            run += ((nbin[s] + 63) >> 6) << 6;
        }
    }
}

// scanC: per-block LDS scan + block offset -> global exclusive prefix (cursor)
__global__ __launch_bounds__(1024) void k_scanC(
    const int* __restrict__ cnt, const int* __restrict__ bsum,
    int* __restrict__ cursor, int N)
{
    __shared__ int lsum[1024];
    const int tid = threadIdx.x;
    const int i = blockIdx.x * 1024 + tid;
    int x = (i < N) ? cnt[i] : 0;
    lsum[tid] = x;
    __syncthreads();
    int acc = x;
    for (int off = 1; off < 1024; off <<= 1) {
        int add = (tid >= off) ? lsum[tid - off] : 0;
        __syncthreads();
        acc += add;
        lsum[tid] = acc;
        __syncthreads();
    }
    if (i < N) cursor[i] = acc - x + bsum[blockIdx.x];
}

// edge scatter: ONE plain 8B store per edge (e,r,s packed into uint64)
// + node species scatter (merged; grid must cover N in one pass)
__global__ __launch_bounds__(256) void k_scatter(
    const int* __restrict__ recv, const int* __restrict__ send,
    int* __restrict__ cursor, unsigned long long* __restrict__ esort, int E,
    const int* __restrict__ specie, int* __restrict__ ncur,
    int* __restrict__ nperm, int N)
{
    __shared__ int lbin[NSP], lbase[NSP], lcur[NSP];
    const int tid = threadIdx.x;
    const int i0 = blockIdx.x * 256 + tid;
    const int stride = gridDim.x * 256;
    for (int e = i0; e < E; e += stride) {
        int r = recv[e];
        int p = atomicAdd(&cursor[r], 1);
        esort[p] = ((unsigned long long)(unsigned int)e << 32)
                 | ((unsigned long long)(unsigned int)r << 16)
                 | (unsigned long long)(unsigned int)send[e];
    }
    if (tid < NSP) { lbin[tid] = 0; lcur[tid] = 0; }
    __syncthreads();
    int sp = -1;
    if (i0 < N) { sp = specie[i0]; atomicAdd(&lbin[sp], 1); }
    __syncthreads();
    if (tid < NSP && lbin[tid] > 0) lbase[tid] = atomicAdd(&ncur[tid], lbin[tid]);
    __syncthreads();
    if (i0 < N) {
        int off = atomicAdd(&lcur[sp], 1);
        nperm[lbase[sp] + off] = i0;
    }
}

// ---- Kernel B: radial MLP (MFMA) + tensor product + sorted run-accumulation ----
// EB=64 / 3 blocks/CU: proven local optimum (EB=32+6/CU regressed 3x, round 7;
// XCD swizzle regressed 6%, round 9 — atomics resolve at memory-side cache, so
// no XCD locality to exploit; natural blockIdx order wins).
__global__ __launch_bounds__(256, 3) void k_edge(
    const float* __restrict__ vecs, const float* __restrict__ re,
    const float* __restrict__ Wr1, const float* __restrict__ Wr2,
    const unsigned long long* __restrict__ esort,
    const half4* __restrict__ comb,
    float* __restrict__ agg_s, float* __restrict__ agg_v, int E)
{
    __shared__ _Float16 h_lds[EB * PADH];   // ~9 KB
    __shared__ _Float16 w_lds[EB * PADN];   // ~40.5 KB
    const int tid = threadIdx.x;
    const int wave = tid >> 6, lane = tid & 63;
    const int l15 = lane & 15, lq = lane >> 4;

    // Persistent B-fragments: this wave's 80-col slice of W_r2 (f16).
    half8 bfrag[5][2];
#pragma unroll
    for (int nt = 0; nt < 5; ++nt)
#pragma unroll
        for (int ks = 0; ks < 2; ++ks)
#pragma unroll
            for (int j = 0; j < 8; ++j) {
                int k = ks * 32 + lq * 8 + j;
                int n = wave * 80 + nt * 16 + l15;
                bfrag[nt][ks][j] = (_Float16)Wr2[k * (NPATH * F) + n];
            }

    float w1r[RDIM];
#pragma unroll
    for (int r = 0; r < RDIM; ++r) w1r[r] = Wr1[r * HDIM + lane];

    const int niter = (E + EB - 1) / EB;
    for (int it = blockIdx.x; it < niter; it += gridDim.x) {
        const int base = it * EB;
        const bool full = (base + EB <= E);
        unsigned long long es[16];

        // --- phase 1: h for this wave's 16 (sorted) edges; lane = hidden unit ---
        if (full) {
            const int ew = base + wave * 16;
#pragma unroll
            for (int j = 0; j < 8; ++j)
                ((int4*)es)[j] = ((const int4*)(esort + ew))[j];
            float4 ra[4], rb[4];
#pragma unroll
            for (int j = 0; j < 4; ++j) {
                const float4* rp = (const float4*)(re + (size_t)ES_E(es[j]) * RDIM);
                ra[j] = rp[0]; rb[j] = rp[1];
            }
#pragma unroll
            for (int t = 0; t < 16; ++t) {
                float4 A = ra[t & 3], B = rb[t & 3];
                if (t < 12) {
                    const float4* rp = (const float4*)(re + (size_t)ES_E(es[t + 4]) * RDIM);
                    ra[t & 3] = rp[0]; rb[t & 3] = rp[1];
                }
                float h = A.x * w1r[0] + A.y * w1r[1] + A.z * w1r[2] + A.w * w1r[3]
                        + B.x * w1r[4] + B.y * w1r[5] + B.z * w1r[6] + B.w * w1r[7];
                h = h / (1.f + __expf(-h));   // silu
                h_lds[(wave * 16 + t) * PADH + lane] = (_Float16)h;
            }
        } else {
            for (int t = 0; t < 16; ++t) {
                const int eloc = wave * 16 + t;
                const int e = base + eloc;
                float h = 0.f;
                if (e < E) {
                    const int pe = ES_E(esort[e]);
                    const float4* rp = (const float4*)(re + (size_t)pe * RDIM);
                    float4 A = rp[0], B = rp[1];
                    h = A.x * w1r[0] + A.y * w1r[1] + A.z * w1r[2] + A.w * w1r[3]
                      + B.x * w1r[4] + B.y * w1r[5] + B.z * w1r[6] + B.w * w1r[7];
                    h = h / (1.f + __expf(-h));
                }
                h_lds[eloc * PADH + lane] = (_Float16)h;
            }
        }
        __syncthreads();

        // --- phase 2: W(64 x 320) = H(64 x 64) @ Wr2(64 x 320) via MFMA ---
        floatx4 c[4][5];
#pragma unroll
        for (int mt = 0; mt < 4; ++mt)
#pragma unroll
            for (int nt = 0; nt < 5; ++nt)
                c[mt][nt] = (floatx4){0.f, 0.f, 0.f, 0.f};
#pragma unroll
        for (int ks = 0; ks < 2; ++ks) {
            half8 a[4];
#pragma unroll
            for (int mt = 0; mt < 4; ++mt)
                a[mt] = *(const half8*)&h_lds[(mt * 16 + l15) * PADH + ks * 32 + lq * 8];
#pragma unroll
            for (int mt = 0; mt < 4; ++mt)
#pragma unroll
                for (int nt = 0; nt < 5; ++nt)
                    c[mt][nt] = __builtin_amdgcn_mfma_f32_16x16x32_f16(
                        a[mt], bfrag[nt][ks], c[mt][nt], 0, 0, 0);
        }
#pragma unroll
        for (int mt = 0; mt < 4; ++mt)
#pragma unroll
            for (int nt = 0; nt < 5; ++nt)
#pragma unroll
                for (int r = 0; r < 4; ++r) {
                    int row = mt * 16 + lq * 4 + r;
                    int col = wave * 80 + nt * 16 + l15;
                    w_lds[row * PADN + col] = (_Float16)c[mt][nt][r];
                }
        __syncthreads();

        // --- phase 3: tensor product + run-accumulate over sorted receivers ---
        if (full) {
            half4 gb[4];
            float vxr[4], vyr[4], vzr[4];
#pragma unroll
            for (int j = 0; j < 4; ++j) {
                gb[j] = comb[(size_t)ES_S(es[j]) * F + lane];
                const float* vp = vecs + (size_t)ES_E(es[j]) * 3;
                vxr[j] = vp[0]; vyr[j] = vp[1]; vzr[j] = vp[2];
            }
            float accs = 0.f, acc0 = 0.f, acc1 = 0.f, acc2 = 0.f;
            int cur = ES_R(es[0]);
#pragma unroll
            for (int t = 0; t < 16; ++t) {
                half4 g = gb[t & 3];
                float vx = vxr[t & 3], vy = vyr[t & 3], vz = vzr[t & 3];
                if (t < 12) {
                    gb[t & 3] = comb[(size_t)ES_S(es[t + 4]) * F + lane];
                    const float* vp = vecs + (size_t)ES_E(es[t + 4]) * 3;
                    vxr[t & 3] = vp[0]; vyr[t & 3] = vp[1]; vzr[t & 3] = vp[2];
                }
                const int eloc = wave * 16 + t;
                float nrm = sqrtf(vx * vx + vy * vy + vz * vz);
                float inv = 1.f / (nrm + 1e-9f);
                float Yx = vx * inv, Yy = vy * inv, Yz = vz * inv;
                float w0  = (float)w_lds[eloc * PADN + 0 * F + lane];
                float w1p = (float)w_lds[eloc * PADN + 1 * F + lane];
                float w2p = (float)w_lds[eloc * PADN + 2 * F + lane];
                float w3p = (float)w_lds[eloc * PADN + 3 * F + lane];
                float w4p = (float)w_lds[eloc * PADN + 4 * F + lane];
                float xs = (float)g[0], x0 = (float)g[1], x1 = (float)g[2], x2 = (float)g[3];
                float dvY = x0 * Yx + x1 * Yy + x2 * Yz;
                float ms = w0 * xs + w3p * dvY;
                float m0 = w1p * xs * Yx + w2p * x0 + w4p * (x1 * Yz - x2 * Yy);
                float m1 = w1p * xs * Yy + w2p * x1 + w4p * (x2 * Yx - x0 * Yz);
                float m2 = w1p * xs * Yz + w2p * x2 + w4p * (x0 * Yy - x1 * Yx);
                const int rt = ES_R(es[t]);
                if (rt != cur) {
                    float* asb = agg_s + (size_t)cur * F;
                    float* avb = agg_v + (size_t)cur * 3 * F;
                    unsafeAtomicAdd(&asb[lane], accs);
                    unsafeAtomicAdd(&avb[lane], acc0);
                    unsafeAtomicAdd(&avb[F + lane], acc1);
                    unsafeAtomicAdd(&avb[2 * F + lane], acc2);
                    accs = acc0 = acc1 = acc2 = 0.f;
                    cur = rt;
                }
                accs += ms; acc0 += m0; acc1 += m1; acc2 += m2;
            }
            {
                float* asb = agg_s + (size_t)cur * F;
                float* avb = agg_v + (size_t)cur * 3 * F;
                unsafeAtomicAdd(&asb[lane], accs);
                unsafeAtomicAdd(&avb[lane], acc0);
                unsafeAtomicAdd(&avb[F + lane], acc1);
                unsafeAtomicAdd(&avb[2 * F + lane], acc2);
            }
        } else {
            for (int t = 0; t < 16; ++t) {
                const int eloc = wave * 16 + t;
                const int e = base + eloc;
                if (e >= E) break;
                const unsigned long long ev = esort[e];
                const int pe = ES_E(ev), snd = ES_S(ev), rcv = ES_R(ev);
                const float* vp = vecs + (size_t)pe * 3;
                float vx = vp[0], vy = vp[1], vz = vp[2];
                float nrm = sqrtf(vx * vx + vy * vy + vz * vz);
                float inv = 1.f / (nrm + 1e-9f);
                float Yx = vx * inv, Yy = vy * inv, Yz = vz * inv;
                half4 g = comb[(size_t)snd * F + lane];
                float w0  = (float)w_lds[eloc * PADN + 0 * F + lane];
                float w1p = (float)w_lds[eloc * PADN + 1 * F + lane];
                float w2p = (float)w_lds[eloc * PADN + 2 * F + lane];
                float w3p = (float)w_lds[eloc * PADN + 3 * F + lane];
                float w4p = (float)w_lds[eloc * PADN + 4 * F + lane];
                float xs = (float)g[0], x0 = (float)g[1], x1 = (float)g[2], x2 = (float)g[3];
                float dvY = x0 * Yx + x1 * Yy + x2 * Yz;
                float ms = w0 * xs + w3p * dvY;
                float m0 = w1p * xs * Yx + w2p * x0 + w4p * (x1 * Yz - x2 * Yy);
                float m1 = w1p * xs * Yy + w2p * x1 + w4p * (x2 * Yx - x0 * Yz);
                float m2 = w1p * xs * Yz + w2p * x2 + w4p * (x0 * Yy - x1 * Yx);
                float* asb = agg_s + (size_t)rcv * F;
                float* avb = agg_v + (size_t)rcv * 3 * F;
                unsafeAtomicAdd(&asb[lane], ms);
                unsafeAtomicAdd(&avb[lane], m0);
                unsafeAtomicAdd(&avb[F + lane], m1);
                unsafeAtomicAdd(&avb[2 * F + lane], m2);
            }
        }
    }
}

// ---- Kernel C (MFMA): linear-down, sym contraction, skip, readout --------------
__global__ __launch_bounds__(256) void k_post_mfma(
    const float* __restrict__ agg_s, const float* __restrict__ agg_v,
    const float* __restrict__ nfs, const float* __restrict__ nfv,
    const float* __restrict__ Wds, const float* __restrict__ Wdv,
    const float* __restrict__ wss, const float* __restrict__ wsv,
    const float* __restrict__ WLs, const float* __restrict__ WLv,
    const float* __restrict__ Wsks, const float* __restrict__ Wskv,
    const float* __restrict__ Wout, const int* __restrict__ specie,
    const int* __restrict__ nperm,
    float* __restrict__ out0, float* __restrict__ out_fs,
    float* __restrict__ out_fv, int N)
{
    __shared__ _Float16 BT[6][64 * PB];     // transposed f16 weights [n][k], 55.3 KB
    __shared__ _Float16 P_lds[4][16 * PB];  // per-wave P transpose tile, 9.2 KB
    const int tid = threadIdx.x;
    const int wave = tid >> 6, lane = tid & 63;
    const int l15 = lane & 15, lq = lane >> 4;
    const int tb0 = blockIdx.x * 64;

    const int nfirst = nperm[tb0];
    const int sp = (nfirst < 0) ? 0 : specie[nfirst];

    // --- stage 6 weight matrices transposed into LDS (once per block) ---
    {
        const float* srcs[6] = { Wds, Wdv,
                                 Wsks + (size_t)sp * F * F, Wskv + (size_t)sp * F * F,
                                 WLs, WLv };
#pragma unroll
        for (int m = 0; m < 6; ++m) {
            const float* W = srcs[m];
#pragma unroll
            for (int rep = 0; rep < 16; ++rep) {
                int id = rep * 256 + tid;           // 0..4095
                int k = id >> 6, n = id & 63;
                BT[m][n * PB + k] = (_Float16)W[k * F + n];
            }
        }
    }
    __syncthreads();

    const int tb = tb0 + wave * 16;
    const int ndA = nperm[tb + l15];        // A-row node for this lane's m=l15
    int ndr[4];
#pragma unroll
    for (int r = 0; r < 4; ++r) ndr[r] = nperm[tb + lq * 4 + r];

#define BFRAG(m, nt, ks) (*(const half8*)&BT[m][((nt) * 16 + l15) * PB + (ks) * 32 + lq * 8])

    // --- skip GEMM: csk[q][nt] = nf @ Wsk  (q: 0=s, 1..3=v components) ---
    floatx4 csk[4][NT];
#pragma unroll
    for (int q = 0; q < 4; ++q)
#pragma unroll
        for (int nt = 0; nt < NT; ++nt) csk[q][nt] = (floatx4){0.f, 0.f, 0.f, 0.f};
#pragma unroll
    for (int ks = 0; ks < 2; ++ks) {
        half8 a_s, a_v0, a_v1, a_v2;
        if (ndA >= 0) {
            a_s  = h8_from_f32(nfs + (size_t)ndA * F + ks * 32 + lq * 8);
            const float* vb = nfv + ((size_t)ndA * F + ks * 32 + lq * 8) * 3;
            a_v0 = h8_from_f32_stride3(vb + 0);
            a_v1 = h8_from_f32_stride3(vb + 1);
            a_v2 = h8_from_f32_stride3(vb + 2);
        } else {
            a_s = a_v0 = a_v1 = a_v2 = h8_zero();
        }
#pragma unroll
        for (int nt = 0; nt < NT; ++nt) {
            half8 bs = BFRAG(2, nt, ks);
            half8 bv = BFRAG(3, nt, ks);
            csk[0][nt] = __builtin_amdgcn_mfma_f32_16x16x32_f16(a_s,  bs, csk[0][nt], 0, 0, 0);
            csk[1][nt] = __builtin_amdgcn_mfma_f32_16x16x32_f16(a_v0, bv, csk[1][nt], 0, 0, 0);
            csk[2][nt] = __builtin_amdgcn_mfma_f32_16x16x32_f16(a_v1, bv, csk[2][nt], 0, 0, 0);
            csk[3][nt] = __builtin_amdgcn_mfma_f32_16x16x32_f16(a_v2, bv, csk[3][nt], 0, 0, 0);
        }
    }

    // --- down GEMM: cdn[q][nt] = agg @ Wd ---
    floatx4 cdn[4][NT];
#pragma unroll
    for (int q = 0; q < 4; ++q)
#pragma unroll
        for (int nt = 0; nt < NT; ++nt) cdn[q][nt] = (floatx4){0.f, 0.f, 0.f, 0.f};
#pragma unroll
    for (int ks = 0; ks < 2; ++ks) {
        half8 a_s, a_v0, a_v1, a_v2;
        if (ndA >= 0) {
            a_s  = h8_from_f32(agg_s + (size_t)ndA * F + ks * 32 + lq * 8);
            const float* vb = agg_v + (size_t)ndA * 3 * F + ks * 32 + lq * 8;
            a_v0 = h8_from_f32(vb);
            a_v1 = h8_from_f32(vb + F);
            a_v2 = h8_from_f32(vb + 2 * F);
        } else {
            a_s = a_v0 = a_v1 = a_v2 = h8_zero();
        }
#pragma unroll
        for (int nt = 0; nt < NT; ++nt) {
            half8 bs = BFRAG(0, nt, ks);
            half8 bv = BFRAG(1, nt, ks);
            cdn[0][nt] = __builtin_amdgcn_mfma_f32_16x16x32_f16(a_s,  bs, cdn[0][nt], 0, 0, 0);
            cdn[1][nt] = __builtin_amdgcn_mfma_f32_16x16x32_f16(a_v0, bv, cdn[1][nt], 0, 0, 0);
            cdn[2][nt] = __builtin_amdgcn_mfma_f32_16x16x32_f16(a_v1, bv, cdn[2][nt], 0, 0, 0);
            cdn[3][nt] = __builtin_amdgcn_mfma_f32_16x16x32_f16(a_v2, bv, cdn[3][nt], 0, 0, 0);
        }
    }

    // --- sym contraction, elementwise in C layout; result overwrites cdn ---
#pragma unroll
    for (int nt = 0; nt < NT; ++nt) {
        const int g = nt * 16 + l15;
        float a0 = wss[(sp * 3 + 0) * F + g];
        float a1 = wss[(sp * 3 + 1) * F + g];
        float a2 = wss[(sp * 3 + 2) * F + g];
        float b0 = wsv[(sp * 2 + 0) * F + g];
        float b1 = wsv[(sp * 2 + 1) * F + g];
#pragma unroll
        for (int r = 0; r < 4; ++r) {
            const float inv = 0.25f;   // 1/sqrt(16)
            float s2  = cdn[0][nt][r] * inv;
            float v20 = cdn[1][nt][r] * inv;
            float v21 = cdn[2][nt][r] * inv;
            float v22 = cdn[3][nt][r] * inv;
            cdn[0][nt][r] = a0 * s2 + a1 * s2 * s2
                          + a2 * (v20 * v20 + v21 * v21 + v22 * v22);
            cdn[1][nt][r] = b0 * v20 + b1 * s2 * v20;
            cdn[2][nt][r] = b0 * v21 + b1 * s2 * v21;
            cdn[3][nt][r] = b0 * v22 + b1 * s2 * v22;
        }
    }

    // --- final GEMM per quantity: csk[q] += P_q @ WL  (via per-wave LDS transpose)
#pragma unroll
    for (int q = 0; q < 4; ++q) {
#pragma unroll
        for (int nt = 0; nt < NT; ++nt)
#pragma unroll
            for (int r = 0; r < 4; ++r)
                P_lds[wave][(lq * 4 + r) * PB + nt * 16 + l15] = (_Float16)cdn[q][nt][r];
        __syncthreads();
        half8 ap0 = *(const half8*)&P_lds[wave][l15 * PB + 0 * 32 + lq * 8];
        half8 ap1 = *(const half8*)&P_lds[wave][l15 * PB + 1 * 32 + lq * 8];
        const int bm = (q == 0) ? 4 : 5;
#pragma unroll
        for (int nt = 0; nt < NT; ++nt) {
            csk[q][nt] = __builtin_amdgcn_mfma_f32_16x16x32_f16(ap0, BFRAG(bm, nt, 0), csk[q][nt], 0, 0, 0);
            csk[q][nt] = __builtin_amdgcn_mfma_f32_16x16x32_f16(ap1, BFRAG(bm, nt, 1), csk[q][nt], 0, 0, 0);
        }
        __syncthreads();
    }
#undef BFRAG

    // --- stores + readout ---
    float wo[NT];
#pragma unroll
    for (int nt = 0; nt < NT; ++nt) wo[nt] = Wout[nt * 16 + l15];
#pragma unroll
    for (int r = 0; r < 4; ++r) {
        const int nd = ndr[r];
        float po = 0.f;
        if (nd >= 0) {
#pragma unroll
            for (int nt = 0; nt < NT; ++nt) {
                const int g = nt * 16 + l15;
                float fs = csk[0][nt][r];
                out_fs[(size_t)nd * F + g] = fs;
                po += fs * wo[nt];
                float* fvp = out_fv + ((size_t)nd * F + g) * 3;
                fvp[0] = csk[1][nt][r];
                fvp[1] = csk[2][nt][r];
                fvp[2] = csk[3][nt][r];
            }
            po += __shfl_xor(po, 1, 64);
            po += __shfl_xor(po, 2, 64);
            po += __shfl_xor(po, 4, 64);
            po += __shfl_xor(po, 8, 64);
            if (l15 == 0) out0[nd] = po;
        }
    }
}

extern "C" void kernel_launch(void* const* d_in, const int* in_sizes, int n_in,
                              void* d_out, int out_size, void* d_ws, size_t ws_size,
                              hipStream_t stream)
{
    const float* vectors = (const float*)d_in[0];
    const float* nfs  = (const float*)d_in[1];
    const float* nfv  = (const float*)d_in[2];
    const float* re   = (const float*)d_in[3];
    const float* Wus  = (const float*)d_in[4];
    const float* Wuv  = (const float*)d_in[5];
    const float* Wr1  = (const float*)d_in[6];
    const float* Wr2  = (const float*)d_in[7];
    const float* Wds  = (const float*)d_in[8];
    const float* Wdv  = (const float*)d_in[9];
    const float* wss  = (const float*)d_in[10];
    const float* wsv  = (const float*)d_in[11];
    const float* WLs  = (const float*)d_in[12];
    const float* WLv  = (const float*)d_in[13];
    const float* Wsks = (const float*)d_in[14];
    const float* Wskv = (const float*)d_in[15];
    const float* Wout = (const float*)d_in[16];
    const int* specie    = (const int*)d_in[17];
    const int* senders   = (const int*)d_in[18];
    const int* receivers = (const int*)d_in[19];

    const int N = in_sizes[1] / F;   // 50000 (< 2^16, required by esort packing)
    const int E = in_sizes[18];      // 800000 (< 2^20)

    const size_t NF = (size_t)N * F;
    const int NPAD_MAX = N + NSP * 64 + 64;   // species runs padded to 64
    // Workspace layout (~84.2 MB, under the 102.4 MB proven-safe footprint):
    //   comb   : NF half4 (8 B)        = 25.6 MB
    //   agg_s  : NF f32                = 12.8 MB
    //   agg_v  : 3NF f32               = 38.4 MB
    //   esort  : E u64                 =  6.4 MB
    //   cnt,nbin,ncur,cursor,bsum,nperm: ~0.6 MB
    half4* comb  = (half4*)d_ws;
    float* agg_s = (float*)((char*)d_ws + NF * sizeof(half4));
    float* agg_v = agg_s + NF;
    unsigned long long* esort = (unsigned long long*)(agg_v + 3 * NF);
    int*   cnt    = (int*)(esort + E);      // [N]
    int*   nbin   = cnt + N;                // [NSP] (zeroed with cnt)
    int*   ncur   = nbin + NSP;             // [NSP]
    int*   cursor = ncur + NSP;             // [N]
    int*   bsum   = cursor + N;             // [<=64]
    int*   nperm  = bsum + 64;              // [NPAD_MAX]

    hipMemsetAsync(agg_s, 0, (size_t)4 * NF * sizeof(float), stream);
    hipMemsetAsync(cnt, 0, (size_t)(N + NSP) * sizeof(int), stream);
    hipMemsetAsync(nperm, 0xFF, (size_t)NPAD_MAX * sizeof(int), stream);

    const int nb64 = (N + 63) / 64;             // k_pre_mfma blocks (782)
    const int nbs = (N + 1023) / 1024;          // scan blocks (49)
    const int nbp = (N + NSP * 64 + 63) / 64;   // k_post_mfma blocks

    k_pre_mfma<<<nb64, 256, 0, stream>>>(nfs, nfv, Wus, Wuv, comb, N,
                                         receivers, cnt, E, specie, nbin);
    k_scanA<<<nbs, 1024, 0, stream>>>(cnt, bsum, N);
    k_scanB<<<1, 64, 0, stream>>>(bsum, nbs, nbin, ncur);
    k_scanC<<<nbs, 1024, 0, stream>>>(cnt, bsum, cursor, N);
    k_scatter<<<1024, 256, 0, stream>>>(receivers, senders, cursor, esort, E,
                                        specie, ncur, nperm, N);
    k_edge<<<2048, 256, 0, stream>>>(vectors, re, Wr1, Wr2, esort,
                                     comb, agg_s, agg_v, E);
    float* out0   = (float*)d_out;
    float* out_fs = out0 + N;
    float* out_fv = out_fs + (size_t)N * F;
    k_post_mfma<<<nbp, 256, 0, stream>>>(agg_s, agg_v, nfs, nfv, Wds, Wdv,
                                         wss, wsv, WLs, WLv, Wsks, Wskv,
                                         Wout, specie, nperm,
                                         out0, out_fs, out_fv, N);
}